// Round 5
// baseline (459.910 us; speedup 1.0000x reference)
//
#include <hip/hip_runtime.h>

// T=2000 frames, B=64 batch, C=256 vocab, L=200 targets.
#define T_FRAMES 2000
#define BATCH    64
#define CVOC     256
#define LTGT     200
#define EPAD     200                  // emit row stride in HALVES (400 B, dense)
#define SEG      20                   // dp: rows per register segment
#define NSEGH    50                   // SEG*NSEGH = 1000 steps per direction
#define NEG_INF  (-1e30f)
#define INV_LN2  1.4426950408889634f
#define LN2      0.6931471805599453f
// emit stores PLAIN fp16 probability p = exp(x - lse). p >= ~e^-10 typical so
// no fp16 flush-to-zero; occasional subnormals lose 1-3 mantissa bits —
// irrelevant vs the 2.16e+02 absmax threshold.

#if __has_builtin(__builtin_amdgcn_exp2f)
__device__ __forceinline__ float fexp2(float x) { return __builtin_amdgcn_exp2f(x); }
#else
__device__ __forceinline__ float fexp2(float x) { return exp2f(x); }
#endif
#if __has_builtin(__builtin_amdgcn_logf)
__device__ __forceinline__ float flog2(float x) { return __builtin_amdgcn_logf(x); }
#else
__device__ __forceinline__ float flog2(float x) { return log2f(x); }
#endif

typedef unsigned long long u64;

// 4 packed fp16 emissions, 8-byte aligned (one global_load_dwordx2).
struct __align__(8) H4 { _Float16 x, y, z, w; };
union HU { u64 u; H4 h; };

// ---------------------------------------------------------------------------
// Prefetch via VOLATILE u64 loads (round-5). Round-2's dp VGPR_Count=56
// proved the compiler sank the ping-pong buffer loads to their use points
// (80 VGPRs of buffers never existed), so each DP step paid unhidden load
// latency. Round-4's inline-asm version crashed (asm "=v" into an array
// element through a pointer defeats SROA -> scratch round-trip of in-flight
// load destinations). Volatile loads achieve the same pinning safely: LLVM
// never sinks/reorders volatile memory ops, the buffers must stay live in
// registers, and the compiler's waitcnt pass inserts precise COUNTED
// s_waitcnt vmcnt(N) before each use — a correct-by-construction pipeline.
// ---------------------------------------------------------------------------
__device__ __forceinline__ u64 ld_row_v(const _Float16* base, int t, int fi) {
    return *(const volatile u64*)(base + (size_t)t * EPAD + fi * 4);
}

// ---------------------------------------------------------------------------
// DPP helpers.
// ---------------------------------------------------------------------------
// wave_shr:1, 0-fill lane 0 — lane i <- lane i-1 (left neighbor).
__device__ __forceinline__ float dpp_shr1_zero(float v) {
    return __int_as_float(__builtin_amdgcn_update_dpp(
        0, __float_as_int(v), 0x138, 0xF, 0xF, true));
}
__device__ __forceinline__ int dpp_shr1_zero_i(int v) {
    return __builtin_amdgcn_update_dpp(0, v, 0x138, 0xF, 0xF, true);
}
// wave_shl:1, 0-fill lane 63 — lane i <- lane i+1 (right neighbor).
__device__ __forceinline__ float dpp_shl1_zero(float v) {
    return __int_as_float(__builtin_amdgcn_update_dpp(
        0, __float_as_int(v), 0x130, 0xF, 0xF, true));
}
__device__ __forceinline__ int dpp_shl1_zero_i(int v) {
    return __builtin_amdgcn_update_dpp(0, v, 0x130, 0xF, 0xF, true);
}
template <int CTRL, int RMASK>
__device__ __forceinline__ float dpp_term(float v) {
    return __int_as_float(__builtin_amdgcn_update_dpp(
        0, __float_as_int(v), CTRL, RMASK, 0xF, true));
}
__device__ __forceinline__ float wave_max(float v) {
    v = fmaxf(v, dpp_term<0x111, 0xF>(v));   // row_shr:1
    v = fmaxf(v, dpp_term<0x112, 0xF>(v));   // row_shr:2
    v = fmaxf(v, dpp_term<0x114, 0xF>(v));   // row_shr:4
    v = fmaxf(v, dpp_term<0x118, 0xF>(v));   // row_shr:8
    v = fmaxf(v, dpp_term<0x142, 0xA>(v));   // row_bcast:15 -> rows 1,3
    v = fmaxf(v, dpp_term<0x143, 0xC>(v));   // row_bcast:31 -> rows 2,3
    return __int_as_float(__builtin_amdgcn_readlane(__float_as_int(v), 63));
}
__device__ __forceinline__ float wave_sum(float v) {
    v += dpp_term<0x111, 0xF>(v);
    v += dpp_term<0x112, 0xF>(v);
    v += dpp_term<0x114, 0xF>(v);
    v += dpp_term<0x118, 0xF>(v);
    v += dpp_term<0x142, 0xA>(v);
    v += dpp_term<0x143, 0xC>(v);
    return __int_as_float(__builtin_amdgcn_readlane(__float_as_int(v), 63));
}

// ---------------------------------------------------------------------------
// Kernel 1: fused log-softmax + target gather -> plain fp16 probabilities.
// ---------------------------------------------------------------------------
__global__ __launch_bounds__(256) void emit_kernel(const float* __restrict__ x,
                                                   const int* __restrict__ targets,
                                                   _Float16* __restrict__ emit) {
    __shared__ float s[16][CVOC];                // 16 KB
    const int w = threadIdx.x >> 6;
    const int lane = threadIdx.x & 63;
    const int r0 = blockIdx.x * 16 + w * 4;      // this wave's 4 rows (r = t*64+b)
    const int li = (lane < 50) ? lane : 49;

    float4 v[4];
#pragma unroll
    for (int k = 0; k < 4; ++k)
        v[k] = ((const float4*)(x + (size_t)(r0 + k) * CVOC))[lane];
    int4 tg[4];
#pragma unroll
    for (int k = 0; k < 4; ++k)
        tg[k] = ((const int4*)(targets + ((r0 + k) & 63) * LTGT))[li];

    float lse2[4];
#pragma unroll
    for (int k = 0; k < 4; ++k) {
        v[k].x *= INV_LN2; v[k].y *= INV_LN2; v[k].z *= INV_LN2; v[k].w *= INV_LN2;
        float m = fmaxf(fmaxf(v[k].x, v[k].y), fmaxf(v[k].z, v[k].w));
        m = wave_max(m);
        float ss = fexp2(v[k].x - m) + fexp2(v[k].y - m) +
                   fexp2(v[k].z - m) + fexp2(v[k].w - m);
        ss = wave_sum(ss);
        lse2[k] = m + flog2(ss);
        ((float4*)&s[w * 4 + k][lane * 4])[0] = v[k];   // same-wave staging
    }

#pragma unroll
    for (int k = 0; k < 4; ++k) {
        if (lane < 50) {
            const int r = r0 + k;
            const int t = r >> 6;
            const int b = r & 63;
            H4 h;
            h.x = (_Float16)fexp2(s[w * 4 + k][tg[k].x] - lse2[k]);
            h.y = (_Float16)fexp2(s[w * 4 + k][tg[k].y] - lse2[k]);
            h.z = (_Float16)fexp2(s[w * 4 + k][tg[k].z] - lse2[k]);
            h.w = (_Float16)fexp2(s[w * 4 + k][tg[k].w] - lse2[k]);
            ((H4*)(emit + ((size_t)b * T_FRAMES + t) * EPAD))[lane] = h;
        }
    }
}

// ---------------------------------------------------------------------------
// Kernel 2: forward/backward split DP (1000 serial steps per direction).
// answer[b] = v . alpha_999 (round-3 derivation; r3-verified, absmax 0).
// Per-lane power-of-2 scale A; renorm every 4 steps. dA = A(neighbor)-A is
// constant between renorms -> hoisted (recomputed only after each renorm).
// ---------------------------------------------------------------------------
// Forward renorm: inactive lanes adopt LEFT neighbor's scale.
__device__ __forceinline__ void renormF(float& z0, float& z1, float& z2, float& z3,
                                        int& A) {
    const float m4 = fmaxf(fmaxf(z0, z1), fmaxf(z2, z3));
    const int Ap = dpp_shr1_zero_i(A);
    const bool act = (m4 > 0.0f);
    const int sh = act ? (127 - ((__float_as_int(m4) >> 23) & 255)) : 0;
    z0 = ldexpf(z0, sh); z1 = ldexpf(z1, sh);
    z2 = ldexpf(z2, sh); z3 = ldexpf(z3, sh);
    A = act ? (A - sh) : Ap;
}
// Backward renorm: inactive lanes adopt RIGHT neighbor's scale.
__device__ __forceinline__ void renormB(float& z0, float& z1, float& z2, float& z3,
                                        int& A) {
    const float m4 = fmaxf(fmaxf(z0, z1), fmaxf(z2, z3));
    const int Ap = dpp_shl1_zero_i(A);
    const bool act = (m4 > 0.0f);
    const int sh = act ? (127 - ((__float_as_int(m4) >> 23) & 255)) : 0;
    z0 = ldexpf(z0, sh); z1 = ldexpf(z1, sh);
    z2 = ldexpf(z2, sh); z3 = ldexpf(z3, sh);
    A = act ? (A - sh) : Ap;
}

__global__ __launch_bounds__(64, 1) void dp2_kernel(const _Float16* __restrict__ emit,
                                                    float4* __restrict__ fz,
                                                    int* __restrict__ fA,
                                                    float4* __restrict__ bz,
                                                    int* __restrict__ bA) {
    const int bid = blockIdx.x;
    const bool bwd = bid >= BATCH;
    const int b = bwd ? (bid - BATCH) : bid;
    const int lane = threadIdx.x;
    const _Float16* base = emit + (size_t)b * T_FRAMES * EPAD;
    const int fi = (lane < 50) ? lane : 49;

    u64 ebA[SEG], ebB[SEG];

    if (!bwd) {
        // ---------------- forward: steps t = 1..1000, capture at t = 999 ----
#pragma unroll
        for (int j = 0; j < SEG; ++j)            // segment 0 in flight
            ebA[j] = ld_row_v(base, 1 + j, fi);

        const float e00 = (float)base[0];
        float z0 = (lane == 0) ? e00 : 0.0f;
        float z1 = 0.0f, z2 = 0.0f, z3 = 0.0f;
        int A = 0;
        renormF(z0, z1, z2, z3, A);
        int dA = dpp_shr1_zero_i(A) - A;

        float r0 = 0.0f, r1 = 0.0f, r2 = 0.0f, r3 = 0.0f;
        int rA = 0;

#define DPF_STEP(eu, cap, j)                                          \
    {                                                                 \
        HU _hu; _hu.u = (eu);                                         \
        const float p  = dpp_shr1_zero(z3);                           \
        const float pe = ldexpf(p, dA);                               \
        const float e0 = (float)_hu.h.x;                              \
        const float e1 = (float)_hu.h.y;                              \
        const float e2 = (float)_hu.h.z;                              \
        const float e3 = (float)_hu.h.w;                              \
        const float n0 = e0 * (z0 + pe);                              \
        const float n1 = e1 * (z1 + z0);                              \
        const float n2 = e2 * (z2 + z1);                              \
        const float n3 = e3 * (z3 + z2);                              \
        z0 = n0; z1 = n1; z2 = n2; z3 = n3;                           \
        if ((cap) && (j) == 18) { r0 = z0; r1 = z1; r2 = z2; r3 = z3; rA = A; } \
        if (((j) & 3) == 3) { renormF(z0, z1, z2, z3, A);             \
                              dA = dpp_shr1_zero_i(A) - A; }          \
    }

        for (int sp = 0; sp < NSEGH; sp += 2) {
#pragma unroll
            for (int j = 0; j < SEG; ++j)        // segment sp+1 in flight
                ebB[j] = ld_row_v(base, 1 + (sp + 1) * SEG + j, fi);
#pragma unroll
            for (int j = 0; j < SEG; ++j) DPF_STEP(ebA[j], false, j);
            if (sp + 2 < NSEGH) {
#pragma unroll
                for (int j = 0; j < SEG; ++j)    // segment sp+2 in flight
                    ebA[j] = ld_row_v(base, 1 + (sp + 2) * SEG + j, fi);
            }
            const bool capB = (sp == NSEGH - 2); // segment 49 holds t=999 at j=18
#pragma unroll
            for (int j = 0; j < SEG; ++j) DPF_STEP(ebB[j], capB, j);
        }
#undef DPF_STEP

        fz[b * 64 + lane] = make_float4(r0, r1, r2, r3);
        fA[b * 64 + lane] = rA;
    } else {
        // ---------------- backward: steps t = 1999 down to 1000 -------------
#pragma unroll
        for (int j = 0; j < SEG; ++j)            // segment 0 in flight
            ebA[j] = ld_row_v(base, 1999 - j, fi);

        float z0 = 0.0f, z1 = 0.0f, z2 = 0.0f;
        float z3 = (lane == 49) ? 1.0f : 0.0f;   // unit at l = 199
        int A = 0;
        int dA = 0;                              // all A equal initially

#define DPB_STEP(eu, j)                                               \
    {                                                                 \
        HU _hu; _hu.u = (eu);                                         \
        const float e0 = (float)_hu.h.x;                              \
        const float e1 = (float)_hu.h.y;                              \
        const float e2 = (float)_hu.h.z;                              \
        const float e3 = (float)_hu.h.w;                              \
        const float w0 = z0 * e0;                                     \
        const float w1 = z1 * e1;                                     \
        const float w2 = z2 * e2;                                     \
        const float w3 = z3 * e3;                                     \
        const float q  = dpp_shl1_zero(w0);                           \
        const float pe = ldexpf(q, dA);                               \
        z0 = w0 + w1; z1 = w1 + w2; z2 = w2 + w3; z3 = w3 + pe;       \
        if (((j) & 3) == 3) { renormB(z0, z1, z2, z3, A);             \
                              dA = dpp_shl1_zero_i(A) - A; }          \
    }

        for (int sp = 0; sp < NSEGH; sp += 2) {
#pragma unroll
            for (int j = 0; j < SEG; ++j)
                ebB[j] = ld_row_v(base, 1999 - ((sp + 1) * SEG + j), fi);
#pragma unroll
            for (int j = 0; j < SEG; ++j) DPB_STEP(ebA[j], j);
            if (sp + 2 < NSEGH) {
#pragma unroll
                for (int j = 0; j < SEG; ++j)
                    ebA[j] = ld_row_v(base, 1999 - ((sp + 2) * SEG + j), fi);
            }
#pragma unroll
            for (int j = 0; j < SEG; ++j) DPB_STEP(ebB[j], j);
        }
#undef DPB_STEP

        bz[b * 64 + lane] = make_float4(z0, z1, z2, z3);
        bA[b * 64 + lane] = A;
    }
}

// ---------------------------------------------------------------------------
// Kernel 3: combine — scaled dot of alpha_999 and the backward row, logsumexp
// across lanes.
// ---------------------------------------------------------------------------
__global__ __launch_bounds__(64) void combine_kernel(const float4* __restrict__ fz,
                                                     const int* __restrict__ fA,
                                                     const float4* __restrict__ bz,
                                                     const int* __restrict__ bA,
                                                     float* __restrict__ part) {
    const int b = blockIdx.x;
    const int lane = threadIdx.x;
    const float4 f = fz[b * 64 + lane];
    const float4 g = bz[b * 64 + lane];
    const float s = f.x * g.x + f.y * g.y + f.z * g.z + f.w * g.w;
    float tl = (lane < 50 && s > 0.0f)
                   ? flog2(s) + (float)(fA[b * 64 + lane] + bA[b * 64 + lane])
                   : -3.0e38f;
    float m = tl;
#pragma unroll
    for (int d = 1; d < 64; d <<= 1) m = fmaxf(m, __shfl_xor(m, d, 64));
    float p = fexp2(tl - m);
#pragma unroll
    for (int d = 1; d < 64; d <<= 1) p += __shfl_xor(p, d, 64);
    if (lane == 0) part[b] = -(m + flog2(p)) * LN2;   // back to nats
}

// ---------------------------------------------------------------------------
// Kernel 4: mean over the 64 per-batch NLLs.
// ---------------------------------------------------------------------------
__global__ __launch_bounds__(64) void reduce_kernel(const float* __restrict__ part,
                                                    float* __restrict__ out) {
    float v = part[threadIdx.x];
#pragma unroll
    for (int s = 1; s < 64; s <<= 1) v += __shfl_xor(v, s, 64);
    if (threadIdx.x == 0) out[0] = v * (1.0f / BATCH);
}

// ===========================================================================
// Fallback path (round-1, natural-log domain, verified) if ws too small.
// ===========================================================================
__device__ __forceinline__ float lae(float a, float b) {
    float m = fmaxf(a, b);
    float d = fminf(a, b) - m;
    return m + __logf(1.0f + __expf(d));
}

__global__ __launch_bounds__(256) void lse_kernel(const float* __restrict__ x,
                                                  float* __restrict__ lse) {
    const int wave = threadIdx.x >> 6;
    const int lane = threadIdx.x & 63;
    const int r = blockIdx.x * 4 + wave;
    float4 v = ((const float4*)(x + (size_t)r * CVOC))[lane];
    float m = fmaxf(fmaxf(v.x, v.y), fmaxf(v.z, v.w));
#pragma unroll
    for (int s = 1; s < 64; s <<= 1) m = fmaxf(m, __shfl_xor(m, s, 64));
    float ssum = __expf(v.x - m) + __expf(v.y - m) + __expf(v.z - m) + __expf(v.w - m);
#pragma unroll
    for (int s = 1; s < 64; s <<= 1) ssum += __shfl_xor(ssum, s, 64);
    if (lane == 0) {
        const int t = r >> 6;
        const int b = r & 63;
        lse[b * T_FRAMES + t] = m + __logf(ssum);
    }
}

__global__ __launch_bounds__(64) void dp_slow_kernel(const float* __restrict__ x,
                                                     const int* __restrict__ targets,
                                                     const float* __restrict__ lse,
                                                     float* __restrict__ part) {
    __shared__ float s_lse[T_FRAMES];
    const int b = blockIdx.x;
    const int lane = threadIdx.x;
    for (int i = lane; i < T_FRAMES; i += 64) s_lse[i] = lse[b * T_FRAMES + i];
    const int* tg = targets + b * LTGT;
    const int l0 = lane * 4;
    const int i0 = tg[(l0 + 0 < LTGT) ? (l0 + 0) : (LTGT - 1)];
    const int i1 = tg[(l0 + 1 < LTGT) ? (l0 + 1) : (LTGT - 1)];
    const int i2 = tg[(l0 + 2 < LTGT) ? (l0 + 2) : (LTGT - 1)];
    const int i3 = tg[(l0 + 3 < LTGT) ? (l0 + 3) : (LTGT - 1)];
    const float* xb = x + b * CVOC;
    __syncthreads();
    float a0 = (lane == 0) ? (xb[i0] - s_lse[0]) : NEG_INF;
    float a1 = NEG_INF, a2 = NEG_INF, a3 = NEG_INF;
    const float* rA = xb + (size_t)1 * BATCH * CVOC;
    float pa0 = rA[i0], pa1 = rA[i1], pa2 = rA[i2], pa3 = rA[i3];
    const float* rB = xb + (size_t)2 * BATCH * CVOC;
    float pb0 = rB[i0], pb1 = rB[i1], pb2 = rB[i2], pb3 = rB[i3];
#define DP_STEP(e0, e1, e2, e3, tt)                                   \
    {                                                                 \
        const float ls = s_lse[tt];                                   \
        float prev = __shfl_up(a3, 1, 64);                            \
        if (lane == 0) prev = NEG_INF;                                \
        const float n0 = ((e0) - ls) + lae(a0, prev);                 \
        const float n1 = ((e1) - ls) + lae(a1, a0);                   \
        const float n2 = ((e2) - ls) + lae(a2, a1);                   \
        const float n3 = ((e3) - ls) + lae(a3, a2);                   \
        a0 = n0; a1 = n1; a2 = n2; a3 = n3;                           \
    }
    int t = 1;
    while (t < T_FRAMES) {
        DP_STEP(pa0, pa1, pa2, pa3, t);
        {
            const int tn = (t + 2 < T_FRAMES) ? (t + 2) : (T_FRAMES - 1);
            const float* r = xb + (size_t)tn * BATCH * CVOC;
            pa0 = r[i0]; pa1 = r[i1]; pa2 = r[i2]; pa3 = r[i3];
        }
        ++t;
        if (t >= T_FRAMES) break;
        DP_STEP(pb0, pb1, pb2, pb3, t);
        {
            const int tn = (t + 2 < T_FRAMES) ? (t + 2) : (T_FRAMES - 1);
            const float* r = xb + (size_t)tn * BATCH * CVOC;
            pb0 = r[i0]; pb1 = r[i1]; pb2 = r[i2]; pb3 = r[i3];
        }
        ++t;
    }
#undef DP_STEP
    const float resv = __shfl(a3, 49, 64);
    if (lane == 0) part[b] = -resv;
}

extern "C" void kernel_launch(void* const* d_in, const int* in_sizes, int n_in,
                              void* d_out, int out_size, void* d_ws, size_t ws_size,
                              hipStream_t stream) {
    const float* x = (const float*)d_in[0];        // [T, B, C] float32
    const int* targets = (const int*)d_in[1];      // [B, L] int32
    float* out = (float*)d_out;

    const size_t emit_bytes = (size_t)BATCH * T_FRAMES * EPAD * sizeof(_Float16); // 51.2 MB
    const size_t off_part = emit_bytes + 4096;
    const size_t off_fz   = emit_bytes + 8192;               // 16B aligned
    const size_t off_fA   = off_fz + (size_t)BATCH * 64 * 16;
    const size_t off_bz   = off_fA + (size_t)BATCH * 64 * 4;
    const size_t off_bA   = off_bz + (size_t)BATCH * 64 * 16;
    const size_t need     = off_bA + (size_t)BATCH * 64 * 4 + 4096;

    if (ws_size >= need) {
        _Float16* emit = (_Float16*)d_ws;
        float*  part = (float*)((char*)d_ws + off_part);
        float4* fz   = (float4*)((char*)d_ws + off_fz);
        int*    fAi  = (int*)((char*)d_ws + off_fA);
        float4* bz   = (float4*)((char*)d_ws + off_bz);
        int*    bAi  = (int*)((char*)d_ws + off_bA);
        emit_kernel<<<T_FRAMES * BATCH / 16, 256, 0, stream>>>(x, targets, emit);
        dp2_kernel<<<2 * BATCH, 64, 0, stream>>>(emit, fz, fAi, bz, bAi);
        combine_kernel<<<BATCH, 64, 0, stream>>>(fz, fAi, bz, bAi, part);
        reduce_kernel<<<1, 64, 0, stream>>>(part, out);
    } else {
        float* lse = (float*)d_ws;
        float* part = lse + (size_t)BATCH * T_FRAMES;
        lse_kernel<<<T_FRAMES * BATCH / 4, 256, 0, stream>>>(x, lse);
        dp_slow_kernel<<<BATCH, 64, 0, stream>>>(x, targets, lse, part);
        reduce_kernel<<<1, 64, 0, stream>>>(part, out);
    }
}

// Round 7
// 364.470 us; speedup vs baseline: 1.2619x; 1.2619x over previous
//
#include <hip/hip_runtime.h>

// T=2000 frames, B=64 batch, C=256 vocab, L=200 targets.
#define T_FRAMES 2000
#define BATCH    64
#define CVOC     256
#define LTGT     200
#define EPAD     200                  // emit row stride in HALVES (400 B, dense)
#define SEG      20                   // dp: rows per LDS segment
#define NSEGH    50                   // SEG*NSEGH = 1000 steps per direction
#define NEG_INF  (-1e30f)
#define INV_LN2  1.4426950408889634f
#define LN2      0.6931471805599453f
// emit stores PLAIN fp16 probability p = exp(x - lse). p >= ~e^-10 typical so
// no fp16 flush-to-zero; occasional subnormals lose 1-3 mantissa bits —
// irrelevant vs the 2.16e+02 absmax threshold.

#if __has_builtin(__builtin_amdgcn_exp2f)
__device__ __forceinline__ float fexp2(float x) { return __builtin_amdgcn_exp2f(x); }
#else
__device__ __forceinline__ float fexp2(float x) { return exp2f(x); }
#endif
#if __has_builtin(__builtin_amdgcn_logf)
__device__ __forceinline__ float flog2(float x) { return __builtin_amdgcn_logf(x); }
#else
__device__ __forceinline__ float flog2(float x) { return log2f(x); }
#endif

typedef unsigned long long u64;

// 4 packed fp16 emissions, 8-byte aligned (one global_load_dwordx2 / ds_read_b64).
struct __align__(8) H4 { _Float16 x, y, z, w; };
union HU { u64 u; H4 h; };

// ---------------------------------------------------------------------------
// Round-7 dp2: producer/consumer wave specialization via LDS double-buffer.
// History of the latency fight: r2 plain loads -> IR sinks them to uses
// (VGPR=56, ~90 stall cyc/step). r4 asm into array-elems -> scratch round-trip
// crash. r5 volatile -> backend drains vmcnt per load (600 cyc/load, 266 us).
// r6 asm into named scalars -> container failure (cause unresolved; asm path
// abandoned). This round: wave 1 stages each 20-row segment into LDS; wave 0
// computes from LDS. __syncthreads() at segment boundaries blocks IR load
// sinking (what killed r2), the producer's 16 independent loads/lane pipeline
// naturally, and the consumer's ds_read_b64 gets compiler-counted lgkmcnt
// (the one scheduling job hipcc provably does well — guide §5/m97). Plain
// HIP, no asm, numerics byte-identical to the r3/r5-verified step macros.
// ---------------------------------------------------------------------------
// Stage rows t0..t0+19 (ascending) of a [T][50]-u64 emit panel into dst[0..999].
__device__ __forceinline__ void stage_seg(u64* dst, const char* bbase,
                                          int t0, int lane) {
#pragma unroll
    for (int k = 0; k < 15; ++k) {
        const int i = lane + k * 64;
        const int r = i / 50;
        const int c = i - r * 50;
        dst[i] = *(const u64*)(bbase + (size_t)(t0 + r) * 400 + (size_t)c * 8);
    }
    const int i15 = lane + 960;
    if (i15 < 1000) {
        const int r = i15 / 50;
        const int c = i15 - r * 50;
        dst[i15] = *(const u64*)(bbase + (size_t)(t0 + r) * 400 + (size_t)c * 8);
    }
}

// ---------------------------------------------------------------------------
// DPP helpers.
// ---------------------------------------------------------------------------
// wave_shr:1, 0-fill lane 0 — lane i <- lane i-1 (left neighbor).
__device__ __forceinline__ float dpp_shr1_zero(float v) {
    return __int_as_float(__builtin_amdgcn_update_dpp(
        0, __float_as_int(v), 0x138, 0xF, 0xF, true));
}
__device__ __forceinline__ int dpp_shr1_zero_i(int v) {
    return __builtin_amdgcn_update_dpp(0, v, 0x138, 0xF, 0xF, true);
}
// wave_shl:1, 0-fill lane 63 — lane i <- lane i+1 (right neighbor).
__device__ __forceinline__ float dpp_shl1_zero(float v) {
    return __int_as_float(__builtin_amdgcn_update_dpp(
        0, __float_as_int(v), 0x130, 0xF, 0xF, true));
}
__device__ __forceinline__ int dpp_shl1_zero_i(int v) {
    return __builtin_amdgcn_update_dpp(0, v, 0x130, 0xF, 0xF, true);
}
template <int CTRL, int RMASK>
__device__ __forceinline__ float dpp_term(float v) {
    return __int_as_float(__builtin_amdgcn_update_dpp(
        0, __float_as_int(v), CTRL, RMASK, 0xF, true));
}
__device__ __forceinline__ float wave_max(float v) {
    v = fmaxf(v, dpp_term<0x111, 0xF>(v));   // row_shr:1
    v = fmaxf(v, dpp_term<0x112, 0xF>(v));   // row_shr:2
    v = fmaxf(v, dpp_term<0x114, 0xF>(v));   // row_shr:4
    v = fmaxf(v, dpp_term<0x118, 0xF>(v));   // row_shr:8
    v = fmaxf(v, dpp_term<0x142, 0xA>(v));   // row_bcast:15 -> rows 1,3
    v = fmaxf(v, dpp_term<0x143, 0xC>(v));   // row_bcast:31 -> rows 2,3
    return __int_as_float(__builtin_amdgcn_readlane(__float_as_int(v), 63));
}
__device__ __forceinline__ float wave_sum(float v) {
    v += dpp_term<0x111, 0xF>(v);
    v += dpp_term<0x112, 0xF>(v);
    v += dpp_term<0x114, 0xF>(v);
    v += dpp_term<0x118, 0xF>(v);
    v += dpp_term<0x142, 0xA>(v);
    v += dpp_term<0x143, 0xC>(v);
    return __int_as_float(__builtin_amdgcn_readlane(__float_as_int(v), 63));
}

// ---------------------------------------------------------------------------
// Kernel 1: fused log-softmax + target gather -> plain fp16 probabilities.
// ---------------------------------------------------------------------------
__global__ __launch_bounds__(256) void emit_kernel(const float* __restrict__ x,
                                                   const int* __restrict__ targets,
                                                   _Float16* __restrict__ emit) {
    __shared__ float s[16][CVOC];                // 16 KB
    const int w = threadIdx.x >> 6;
    const int lane = threadIdx.x & 63;
    const int r0 = blockIdx.x * 16 + w * 4;      // this wave's 4 rows (r = t*64+b)
    const int li = (lane < 50) ? lane : 49;

    float4 v[4];
#pragma unroll
    for (int k = 0; k < 4; ++k)
        v[k] = ((const float4*)(x + (size_t)(r0 + k) * CVOC))[lane];
    int4 tg[4];
#pragma unroll
    for (int k = 0; k < 4; ++k)
        tg[k] = ((const int4*)(targets + ((r0 + k) & 63) * LTGT))[li];

    float lse2[4];
#pragma unroll
    for (int k = 0; k < 4; ++k) {
        v[k].x *= INV_LN2; v[k].y *= INV_LN2; v[k].z *= INV_LN2; v[k].w *= INV_LN2;
        float m = fmaxf(fmaxf(v[k].x, v[k].y), fmaxf(v[k].z, v[k].w));
        m = wave_max(m);
        float ss = fexp2(v[k].x - m) + fexp2(v[k].y - m) +
                   fexp2(v[k].z - m) + fexp2(v[k].w - m);
        ss = wave_sum(ss);
        lse2[k] = m + flog2(ss);
        ((float4*)&s[w * 4 + k][lane * 4])[0] = v[k];   // same-wave staging
    }

#pragma unroll
    for (int k = 0; k < 4; ++k) {
        if (lane < 50) {
            const int r = r0 + k;
            const int t = r >> 6;
            const int b = r & 63;
            H4 h;
            h.x = (_Float16)fexp2(s[w * 4 + k][tg[k].x] - lse2[k]);
            h.y = (_Float16)fexp2(s[w * 4 + k][tg[k].y] - lse2[k]);
            h.z = (_Float16)fexp2(s[w * 4 + k][tg[k].z] - lse2[k]);
            h.w = (_Float16)fexp2(s[w * 4 + k][tg[k].w] - lse2[k]);
            ((H4*)(emit + ((size_t)b * T_FRAMES + t) * EPAD))[lane] = h;
        }
    }
}

// ---------------------------------------------------------------------------
// Kernel 2: forward/backward split DP (1000 serial steps per direction),
// 2 waves/block: wave 0 computes, wave 1 stages segments into LDS dbuf.
// answer[b] = v . alpha_999 (round-3 derivation; r3-verified, absmax 0).
// Per-lane power-of-2 scale A; renorm every 4 steps. dA = A(neighbor)-A is
// constant between renorms -> hoisted (r5-verified variant).
// ---------------------------------------------------------------------------
// Forward renorm: inactive lanes adopt LEFT neighbor's scale.
__device__ __forceinline__ void renormF(float& z0, float& z1, float& z2, float& z3,
                                        int& A) {
    const float m4 = fmaxf(fmaxf(z0, z1), fmaxf(z2, z3));
    const int Ap = dpp_shr1_zero_i(A);
    const bool act = (m4 > 0.0f);
    const int sh = act ? (127 - ((__float_as_int(m4) >> 23) & 255)) : 0;
    z0 = ldexpf(z0, sh); z1 = ldexpf(z1, sh);
    z2 = ldexpf(z2, sh); z3 = ldexpf(z3, sh);
    A = act ? (A - sh) : Ap;
}
// Backward renorm: inactive lanes adopt RIGHT neighbor's scale.
__device__ __forceinline__ void renormB(float& z0, float& z1, float& z2, float& z3,
                                        int& A) {
    const float m4 = fmaxf(fmaxf(z0, z1), fmaxf(z2, z3));
    const int Ap = dpp_shl1_zero_i(A);
    const bool act = (m4 > 0.0f);
    const int sh = act ? (127 - ((__float_as_int(m4) >> 23) & 255)) : 0;
    z0 = ldexpf(z0, sh); z1 = ldexpf(z1, sh);
    z2 = ldexpf(z2, sh); z3 = ldexpf(z3, sh);
    A = act ? (A - sh) : Ap;
}

__global__ __launch_bounds__(128, 1) void dp2_kernel(const _Float16* __restrict__ emit,
                                                     float4* __restrict__ fz,
                                                     int* __restrict__ fA,
                                                     float4* __restrict__ bz,
                                                     int* __restrict__ bA) {
    __shared__ u64 buf[2][SEG * 50];             // 16 KB double buffer
    const int bid = blockIdx.x;
    const bool bwd = bid >= BATCH;
    const int b = bwd ? (bid - BATCH) : bid;
    const int wv = threadIdx.x >> 6;             // 0 = compute, 1 = producer
    const int lane = threadIdx.x & 63;
    const _Float16* base = emit + (size_t)b * T_FRAMES * EPAD;
    const char* bbase = (const char*)base;
    const int fi = (lane < 50) ? lane : 49;

    // Segment anchors (rows staged ASCENDING in t within each segment):
    //  forward  seg s: t = 1+20s .. 20+20s      -> step j uses LDS row j
    //  backward seg s: t = 1980-20s .. 1999-20s -> step j (t=1999-20s-j) uses row 19-j
    const int t0_0 = bwd ? 1980 : 1;

    // compute-wave state (wave 1 carries dead copies; no cost)
    float z0 = 0.0f, z1 = 0.0f, z2 = 0.0f, z3 = 0.0f;
    int A = 0, dA = 0;
    float r0 = 0.0f, r1 = 0.0f, r2 = 0.0f, r3 = 0.0f;
    int rA = 0;

    if (wv == 0) {
        if (!bwd) {
            const float e00 = (float)base[0];    // row t=0, element 0
            z0 = (lane == 0) ? e00 : 0.0f;
            renormF(z0, z1, z2, z3, A);
            dA = dpp_shr1_zero_i(A) - A;
        } else {
            z3 = (lane == 49) ? 1.0f : 0.0f;     // unit at l = 199
        }
    } else {
        stage_seg(buf[0], bbase, t0_0, lane);    // prologue: segment 0
    }
    __syncthreads();

#define DPF_STEP(eu, cap, j)                                          \
    {                                                                 \
        HU _hu; _hu.u = (eu);                                         \
        const float pv = dpp_shr1_zero(z3);                           \
        const float pe = ldexpf(pv, dA);                              \
        const float e0 = (float)_hu.h.x;                              \
        const float e1 = (float)_hu.h.y;                              \
        const float e2 = (float)_hu.h.z;                              \
        const float e3 = (float)_hu.h.w;                              \
        const float n0 = e0 * (z0 + pe);                              \
        const float n1 = e1 * (z1 + z0);                              \
        const float n2 = e2 * (z2 + z1);                              \
        const float n3 = e3 * (z3 + z2);                              \
        z0 = n0; z1 = n1; z2 = n2; z3 = n3;                           \
        if ((cap) && (j) == 18) { r0 = z0; r1 = z1; r2 = z2; r3 = z3; rA = A; } \
        if (((j) & 3) == 3) { renormF(z0, z1, z2, z3, A);             \
                              dA = dpp_shr1_zero_i(A) - A; }          \
    }
#define DPB_STEP(eu, j)                                               \
    {                                                                 \
        HU _hu; _hu.u = (eu);                                         \
        const float e0 = (float)_hu.h.x;                              \
        const float e1 = (float)_hu.h.y;                              \
        const float e2 = (float)_hu.h.z;                              \
        const float e3 = (float)_hu.h.w;                              \
        const float w0 = z0 * e0;                                     \
        const float w1 = z1 * e1;                                     \
        const float w2 = z2 * e2;                                     \
        const float w3 = z3 * e3;                                     \
        const float q  = dpp_shl1_zero(w0);                           \
        const float pe = ldexpf(q, dA);                               \
        z0 = w0 + w1; z1 = w1 + w2; z2 = w2 + w3; z3 = w3 + pe;       \
        if (((j) & 3) == 3) { renormB(z0, z1, z2, z3, A);             \
                              dA = dpp_shl1_zero_i(A) - A; }          \
    }

    for (int s = 0; s < NSEGH; ++s) {
        const u64* cur = buf[s & 1];
        if (wv == 1) {
            if (s + 1 < NSEGH)
                stage_seg(buf[(s + 1) & 1], bbase,
                          bwd ? (1980 - 20 * (s + 1)) : (1 + 20 * (s + 1)), lane);
        } else if (!bwd) {
            const bool cap = (s == NSEGH - 1);   // seg 49 holds t=999 at j=18
#pragma unroll
            for (int j = 0; j < SEG; ++j) DPF_STEP(cur[j * 50 + fi], cap, j);
        } else {
#pragma unroll
            for (int j = 0; j < SEG; ++j) DPB_STEP(cur[(19 - j) * 50 + fi], j);
        }
        __syncthreads();
    }
#undef DPF_STEP
#undef DPB_STEP

    if (wv == 0) {
        if (!bwd) {
            fz[b * 64 + lane] = make_float4(r0, r1, r2, r3);
            fA[b * 64 + lane] = rA;
        } else {
            bz[b * 64 + lane] = make_float4(z0, z1, z2, z3);
            bA[b * 64 + lane] = A;
        }
    }
}

// ---------------------------------------------------------------------------
// Kernel 3: combine — scaled dot of alpha_999 and the backward row, logsumexp
// across lanes.
// ---------------------------------------------------------------------------
__global__ __launch_bounds__(64) void combine_kernel(const float4* __restrict__ fz,
                                                     const int* __restrict__ fA,
                                                     const float4* __restrict__ bz,
                                                     const int* __restrict__ bA,
                                                     float* __restrict__ part) {
    const int b = blockIdx.x;
    const int lane = threadIdx.x;
    const float4 f = fz[b * 64 + lane];
    const float4 g = bz[b * 64 + lane];
    const float s = f.x * g.x + f.y * g.y + f.z * g.z + f.w * g.w;
    float tl = (lane < 50 && s > 0.0f)
                   ? flog2(s) + (float)(fA[b * 64 + lane] + bA[b * 64 + lane])
                   : -3.0e38f;
    float m = tl;
#pragma unroll
    for (int d = 1; d < 64; d <<= 1) m = fmaxf(m, __shfl_xor(m, d, 64));
    float p = fexp2(tl - m);
#pragma unroll
    for (int d = 1; d < 64; d <<= 1) p += __shfl_xor(p, d, 64);
    if (lane == 0) part[b] = -(m + flog2(p)) * LN2;   // back to nats
}

// ---------------------------------------------------------------------------
// Kernel 4: mean over the 64 per-batch NLLs.
// ---------------------------------------------------------------------------
__global__ __launch_bounds__(64) void reduce_kernel(const float* __restrict__ part,
                                                    float* __restrict__ out) {
    float v = part[threadIdx.x];
#pragma unroll
    for (int s = 1; s < 64; s <<= 1) v += __shfl_xor(v, s, 64);
    if (threadIdx.x == 0) out[0] = v * (1.0f / BATCH);
}

// ===========================================================================
// Fallback path (round-1, natural-log domain, verified) if ws too small.
// ===========================================================================
__device__ __forceinline__ float lae(float a, float b) {
    float m = fmaxf(a, b);
    float d = fminf(a, b) - m;
    return m + __logf(1.0f + __expf(d));
}

__global__ __launch_bounds__(256) void lse_kernel(const float* __restrict__ x,
                                                  float* __restrict__ lse) {
    const int wave = threadIdx.x >> 6;
    const int lane = threadIdx.x & 63;
    const int r = blockIdx.x * 4 + wave;
    float4 v = ((const float4*)(x + (size_t)r * CVOC))[lane];
    float m = fmaxf(fmaxf(v.x, v.y), fmaxf(v.z, v.w));
#pragma unroll
    for (int s = 1; s < 64; s <<= 1) m = fmaxf(m, __shfl_xor(m, s, 64));
    float ssum = __expf(v.x - m) + __expf(v.y - m) + __expf(v.z - m) + __expf(v.w - m);
#pragma unroll
    for (int s = 1; s < 64; s <<= 1) ssum += __shfl_xor(ssum, s, 64);
    if (lane == 0) {
        const int t = r >> 6;
        const int b = r & 63;
        lse[b * T_FRAMES + t] = m + __logf(ssum);
    }
}

__global__ __launch_bounds__(64) void dp_slow_kernel(const float* __restrict__ x,
                                                     const int* __restrict__ targets,
                                                     const float* __restrict__ lse,
                                                     float* __restrict__ part) {
    __shared__ float s_lse[T_FRAMES];
    const int b = blockIdx.x;
    const int lane = threadIdx.x;
    for (int i = lane; i < T_FRAMES; i += 64) s_lse[i] = lse[b * T_FRAMES + i];
    const int* tg = targets + b * LTGT;
    const int l0 = lane * 4;
    const int i0 = tg[(l0 + 0 < LTGT) ? (l0 + 0) : (LTGT - 1)];
    const int i1 = tg[(l0 + 1 < LTGT) ? (l0 + 1) : (LTGT - 1)];
    const int i2 = tg[(l0 + 2 < LTGT) ? (l0 + 2) : (LTGT - 1)];
    const int i3 = tg[(l0 + 3 < LTGT) ? (l0 + 3) : (LTGT - 1)];
    const float* xb = x + b * CVOC;
    __syncthreads();
    float a0 = (lane == 0) ? (xb[i0] - s_lse[0]) : NEG_INF;
    float a1 = NEG_INF, a2 = NEG_INF, a3 = NEG_INF;
    const float* rA = xb + (size_t)1 * BATCH * CVOC;
    float pa0 = rA[i0], pa1 = rA[i1], pa2 = rA[i2], pa3 = rA[i3];
    const float* rB = xb + (size_t)2 * BATCH * CVOC;
    float pb0 = rB[i0], pb1 = rB[i1], pb2 = rB[i2], pb3 = rB[i3];
#define DP_STEP(e0, e1, e2, e3, tt)                                   \
    {                                                                 \
        const float ls = s_lse[tt];                                   \
        float prev = __shfl_up(a3, 1, 64);                            \
        if (lane == 0) prev = NEG_INF;                                \
        const float n0 = ((e0) - ls) + lae(a0, prev);                 \
        const float n1 = ((e1) - ls) + lae(a1, a0);                   \
        const float n2 = ((e2) - ls) + lae(a2, a1);                   \
        const float n3 = ((e3) - ls) + lae(a3, a2);                   \
        a0 = n0; a1 = n1; a2 = n2; a3 = n3;                           \
    }
    int t = 1;
    while (t < T_FRAMES) {
        DP_STEP(pa0, pa1, pa2, pa3, t);
        {
            const int tn = (t + 2 < T_FRAMES) ? (t + 2) : (T_FRAMES - 1);
            const float* r = xb + (size_t)tn * BATCH * CVOC;
            pa0 = r[i0]; pa1 = r[i1]; pa2 = r[i2]; pa3 = r[i3];
        }
        ++t;
        if (t >= T_FRAMES) break;
        DP_STEP(pb0, pb1, pb2, pb3, t);
        {
            const int tn = (t + 2 < T_FRAMES) ? (t + 2) : (T_FRAMES - 1);
            const float* r = xb + (size_t)tn * BATCH * CVOC;
            pb0 = r[i0]; pb1 = r[i1]; pb2 = r[i2]; pb3 = r[i3];
        }
        ++t;
    }
#undef DP_STEP
    const float resv = __shfl(a3, 49, 64);
    if (lane == 0) part[b] = -resv;
}

extern "C" void kernel_launch(void* const* d_in, const int* in_sizes, int n_in,
                              void* d_out, int out_size, void* d_ws, size_t ws_size,
                              hipStream_t stream) {
    const float* x = (const float*)d_in[0];        // [T, B, C] float32
    const int* targets = (const int*)d_in[1];      // [B, L] int32
    float* out = (float*)d_out;

    const size_t emit_bytes = (size_t)BATCH * T_FRAMES * EPAD * sizeof(_Float16); // 51.2 MB
    const size_t off_part = emit_bytes + 4096;
    const size_t off_fz   = emit_bytes + 8192;               // 16B aligned
    const size_t off_fA   = off_fz + (size_t)BATCH * 64 * 16;
    const size_t off_bz   = off_fA + (size_t)BATCH * 64 * 4;
    const size_t off_bA   = off_bz + (size_t)BATCH * 64 * 16;
    const size_t need     = off_bA + (size_t)BATCH * 64 * 4 + 4096;

    if (ws_size >= need) {
        _Float16* emit = (_Float16*)d_ws;
        float*  part = (float*)((char*)d_ws + off_part);
        float4* fz   = (float4*)((char*)d_ws + off_fz);
        int*    fAi  = (int*)((char*)d_ws + off_fA);
        float4* bz   = (float4*)((char*)d_ws + off_bz);
        int*    bAi  = (int*)((char*)d_ws + off_bA);
        emit_kernel<<<T_FRAMES * BATCH / 16, 256, 0, stream>>>(x, targets, emit);
        dp2_kernel<<<2 * BATCH, 128, 0, stream>>>(emit, fz, fAi, bz, bAi);
        combine_kernel<<<BATCH, 64, 0, stream>>>(fz, fAi, bz, bAi, part);
        reduce_kernel<<<1, 64, 0, stream>>>(part, out);
    } else {
        float* lse = (float*)d_ws;
        float* part = lse + (size_t)BATCH * T_FRAMES;
        lse_kernel<<<T_FRAMES * BATCH / 4, 256, 0, stream>>>(x, lse);
        dp_slow_kernel<<<BATCH, 64, 0, stream>>>(x, targets, lse, part);
        reduce_kernel<<<1, 64, 0, stream>>>(part, out);
    }
}

// Round 8
// 238.283 us; speedup vs baseline: 1.9301x; 1.5296x over previous
//
#include <hip/hip_runtime.h>

// T=2000 frames, B=64 batch, C=256 vocab, L=200 targets.
#define T_FRAMES 2000
#define BATCH    64
#define CVOC     256
#define LTGT     200
#define EPAD     200                  // emit row stride in HALVES (400 B, dense)
#define SEG      20                   // dp: rows per LDS segment (8000 B contiguous)
#define NSEGH    50                   // SEG*NSEGH = 1000 steps per direction
#define NEG_INF  (-1e30f)
#define INV_LN2  1.4426950408889634f
#define LN2      0.6931471805599453f
// emit stores PLAIN fp16 probability p = exp(x - lse). p >= ~e^-10 typical so
// no fp16 flush-to-zero; occasional subnormals lose 1-3 mantissa bits —
// irrelevant vs the 2.16e+02 absmax threshold.

#if __has_builtin(__builtin_amdgcn_exp2f)
__device__ __forceinline__ float fexp2(float x) { return __builtin_amdgcn_exp2f(x); }
#else
__device__ __forceinline__ float fexp2(float x) { return exp2f(x); }
#endif
#if __has_builtin(__builtin_amdgcn_logf)
__device__ __forceinline__ float flog2(float x) { return __builtin_amdgcn_logf(x); }
#else
__device__ __forceinline__ float flog2(float x) { return log2f(x); }
#endif

typedef unsigned long long u64;

// 4 packed fp16 emissions, 8-byte aligned (one ds_read_b64).
struct __align__(8) H4 { _Float16 x, y, z, w; };
union HU { u64 u; H4 h; };

// ---------------------------------------------------------------------------
// Round-8 staging: async global->LDS, NO VGPR in the path.
// History: r2 plain reg-prefetch -> IR sinks loads to uses (serialized).
// r4 asm-into-array -> scratch crash. r5 volatile -> vmcnt(0) per load
// (600 cyc/load). r7 producer-wave reg-staging -> allocator sank each load
// to its ds_write (VGPR=52, 16x500 cyc/segment = 169 us, measured). Root
// cause in ALL of them: a VGPR destination the compiler may sink or spill.
// global_load_lds has no destination register -> the 8 issues per segment
// cannot be serialized by regalloc; the compiler's own vmcnt(0)+s_barrier
// drain at __syncthreads gives exact segment semantics (guide §5 CM#1, m97).
// Each segment = 20 contiguous rows x 400 B = 8000 B; staged as 8 x 1024 B
// (64 lanes x 16 B, LDS dest = uniform base + lane*16). 192 B over-read per
// segment stays inside the emit panel except backward seg 0 of the last
// batch, which lands in the 4 KB ws slack before 'part'.
// ---------------------------------------------------------------------------
__device__ __forceinline__ void stage_seg(u64* dst, const char* gseg, int lane) {
#if __has_builtin(__builtin_amdgcn_global_load_lds)
#pragma unroll
    for (int k = 0; k < 8; ++k)
        __builtin_amdgcn_global_load_lds(
            (const __attribute__((address_space(1))) void*)(gseg + k * 1024 + lane * 16),
            (__attribute__((address_space(3))) void*)((char*)dst + k * 1024),
            16, 0, 0);
#else
    // Fallback: direct copy (slower; correctness only).
#pragma unroll
    for (int k = 0; k < 8; ++k) {
        const u64* gq = (const u64*)(gseg + k * 1024);
        u64* lq = dst + k * 128;
        lq[lane * 2]     = gq[lane * 2];
        lq[lane * 2 + 1] = gq[lane * 2 + 1];
    }
#endif
}

// ---------------------------------------------------------------------------
// DPP helpers.
// ---------------------------------------------------------------------------
// wave_shr:1, 0-fill lane 0 — lane i <- lane i-1 (left neighbor).
__device__ __forceinline__ float dpp_shr1_zero(float v) {
    return __int_as_float(__builtin_amdgcn_update_dpp(
        0, __float_as_int(v), 0x138, 0xF, 0xF, true));
}
__device__ __forceinline__ int dpp_shr1_zero_i(int v) {
    return __builtin_amdgcn_update_dpp(0, v, 0x138, 0xF, 0xF, true);
}
// wave_shl:1, 0-fill lane 63 — lane i <- lane i+1 (right neighbor).
__device__ __forceinline__ float dpp_shl1_zero(float v) {
    return __int_as_float(__builtin_amdgcn_update_dpp(
        0, __float_as_int(v), 0x130, 0xF, 0xF, true));
}
__device__ __forceinline__ int dpp_shl1_zero_i(int v) {
    return __builtin_amdgcn_update_dpp(0, v, 0x130, 0xF, 0xF, true);
}
template <int CTRL, int RMASK>
__device__ __forceinline__ float dpp_term(float v) {
    return __int_as_float(__builtin_amdgcn_update_dpp(
        0, __float_as_int(v), CTRL, RMASK, 0xF, true));
}
__device__ __forceinline__ float wave_max(float v) {
    v = fmaxf(v, dpp_term<0x111, 0xF>(v));   // row_shr:1
    v = fmaxf(v, dpp_term<0x112, 0xF>(v));   // row_shr:2
    v = fmaxf(v, dpp_term<0x114, 0xF>(v));   // row_shr:4
    v = fmaxf(v, dpp_term<0x118, 0xF>(v));   // row_shr:8
    v = fmaxf(v, dpp_term<0x142, 0xA>(v));   // row_bcast:15 -> rows 1,3
    v = fmaxf(v, dpp_term<0x143, 0xC>(v));   // row_bcast:31 -> rows 2,3
    return __int_as_float(__builtin_amdgcn_readlane(__float_as_int(v), 63));
}
__device__ __forceinline__ float wave_sum(float v) {
    v += dpp_term<0x111, 0xF>(v);
    v += dpp_term<0x112, 0xF>(v);
    v += dpp_term<0x114, 0xF>(v);
    v += dpp_term<0x118, 0xF>(v);
    v += dpp_term<0x142, 0xA>(v);
    v += dpp_term<0x143, 0xC>(v);
    return __int_as_float(__builtin_amdgcn_readlane(__float_as_int(v), 63));
}

// ---------------------------------------------------------------------------
// Kernel 1: fused log-softmax + target gather -> plain fp16 probabilities.
// ---------------------------------------------------------------------------
__global__ __launch_bounds__(256) void emit_kernel(const float* __restrict__ x,
                                                   const int* __restrict__ targets,
                                                   _Float16* __restrict__ emit) {
    __shared__ float s[16][CVOC];                // 16 KB
    const int w = threadIdx.x >> 6;
    const int lane = threadIdx.x & 63;
    const int r0 = blockIdx.x * 16 + w * 4;      // this wave's 4 rows (r = t*64+b)
    const int li = (lane < 50) ? lane : 49;

    float4 v[4];
#pragma unroll
    for (int k = 0; k < 4; ++k)
        v[k] = ((const float4*)(x + (size_t)(r0 + k) * CVOC))[lane];
    int4 tg[4];
#pragma unroll
    for (int k = 0; k < 4; ++k)
        tg[k] = ((const int4*)(targets + ((r0 + k) & 63) * LTGT))[li];

    float lse2[4];
#pragma unroll
    for (int k = 0; k < 4; ++k) {
        v[k].x *= INV_LN2; v[k].y *= INV_LN2; v[k].z *= INV_LN2; v[k].w *= INV_LN2;
        float m = fmaxf(fmaxf(v[k].x, v[k].y), fmaxf(v[k].z, v[k].w));
        m = wave_max(m);
        float ss = fexp2(v[k].x - m) + fexp2(v[k].y - m) +
                   fexp2(v[k].z - m) + fexp2(v[k].w - m);
        ss = wave_sum(ss);
        lse2[k] = m + flog2(ss);
        ((float4*)&s[w * 4 + k][lane * 4])[0] = v[k];   // same-wave staging
    }

#pragma unroll
    for (int k = 0; k < 4; ++k) {
        if (lane < 50) {
            const int r = r0 + k;
            const int t = r >> 6;
            const int b = r & 63;
            H4 h;
            h.x = (_Float16)fexp2(s[w * 4 + k][tg[k].x] - lse2[k]);
            h.y = (_Float16)fexp2(s[w * 4 + k][tg[k].y] - lse2[k]);
            h.z = (_Float16)fexp2(s[w * 4 + k][tg[k].z] - lse2[k]);
            h.w = (_Float16)fexp2(s[w * 4 + k][tg[k].w] - lse2[k]);
            ((H4*)(emit + ((size_t)b * T_FRAMES + t) * EPAD))[lane] = h;
        }
    }
}

// ---------------------------------------------------------------------------
// Kernel 2: forward/backward split DP (1000 serial steps per direction),
// 2 waves/block: wave 0 computes from LDS, wave 1 stages segments via
// global_load_lds into the LDS double buffer.
// answer[b] = v . alpha_999 (round-3 derivation; r3/r7-verified, absmax 0).
// Per-lane power-of-2 scale A; renorm every 4 steps. dA = A(neighbor)-A is
// constant between renorms -> hoisted (r5/r7-verified variant).
// ---------------------------------------------------------------------------
// Forward renorm: inactive lanes adopt LEFT neighbor's scale.
__device__ __forceinline__ void renormF(float& z0, float& z1, float& z2, float& z3,
                                        int& A) {
    const float m4 = fmaxf(fmaxf(z0, z1), fmaxf(z2, z3));
    const int Ap = dpp_shr1_zero_i(A);
    const bool act = (m4 > 0.0f);
    const int sh = act ? (127 - ((__float_as_int(m4) >> 23) & 255)) : 0;
    z0 = ldexpf(z0, sh); z1 = ldexpf(z1, sh);
    z2 = ldexpf(z2, sh); z3 = ldexpf(z3, sh);
    A = act ? (A - sh) : Ap;
}
// Backward renorm: inactive lanes adopt RIGHT neighbor's scale.
__device__ __forceinline__ void renormB(float& z0, float& z1, float& z2, float& z3,
                                        int& A) {
    const float m4 = fmaxf(fmaxf(z0, z1), fmaxf(z2, z3));
    const int Ap = dpp_shl1_zero_i(A);
    const bool act = (m4 > 0.0f);
    const int sh = act ? (127 - ((__float_as_int(m4) >> 23) & 255)) : 0;
    z0 = ldexpf(z0, sh); z1 = ldexpf(z1, sh);
    z2 = ldexpf(z2, sh); z3 = ldexpf(z3, sh);
    A = act ? (A - sh) : Ap;
}

__global__ __launch_bounds__(128, 1) void dp2_kernel(const _Float16* __restrict__ emit,
                                                     float4* __restrict__ fz,
                                                     int* __restrict__ fA,
                                                     float4* __restrict__ bz,
                                                     int* __restrict__ bA) {
    __shared__ u64 buf[2][1024];                 // 2 x 8192 B (8000 used + tail)
    const int bid = blockIdx.x;
    const bool bwd = bid >= BATCH;
    const int b = bwd ? (bid - BATCH) : bid;
    const int wv = threadIdx.x >> 6;             // 0 = compute, 1 = producer
    const int lane = threadIdx.x & 63;
    const _Float16* base = emit + (size_t)b * T_FRAMES * EPAD;
    const char* bbase = (const char*)base;
    const int fi = (lane < 50) ? lane : 49;

    // Segment anchors (rows staged ASCENDING in t within each segment):
    //  forward  seg s: t = 1+20s .. 20+20s      -> step j uses LDS row j
    //  backward seg s: t = 1980-20s .. 1999-20s -> step j (t=1999-20s-j) uses row 19-j

    // compute-wave state (producer wave carries dead copies; no cost)
    float z0 = 0.0f, z1 = 0.0f, z2 = 0.0f, z3 = 0.0f;
    int A = 0, dA = 0;
    float r0 = 0.0f, r1 = 0.0f, r2 = 0.0f, r3 = 0.0f;
    int rA = 0;

    if (wv == 0) {
        if (!bwd) {
            const float e00 = (float)base[0];    // row t=0, element 0
            z0 = (lane == 0) ? e00 : 0.0f;
            renormF(z0, z1, z2, z3, A);
            dA = dpp_shr1_zero_i(A) - A;
        } else {
            z3 = (lane == 49) ? 1.0f : 0.0f;     // unit at l = 199
        }
    } else {
        const size_t sb0 = (size_t)(bwd ? 1980 : 1) * 400;
        stage_seg(buf[0], bbase + sb0, lane);    // prologue: segment 0
    }
    __syncthreads();                             // drains producer's vmcnt

#define DPF_STEP(eu, cap, j)                                          \
    {                                                                 \
        HU _hu; _hu.u = (eu);                                         \
        const float pv = dpp_shr1_zero(z3);                           \
        const float pe = ldexpf(pv, dA);                              \
        const float e0 = (float)_hu.h.x;                              \
        const float e1 = (float)_hu.h.y;                              \
        const float e2 = (float)_hu.h.z;                              \
        const float e3 = (float)_hu.h.w;                              \
        const float n0 = e0 * (z0 + pe);                              \
        const float n1 = e1 * (z1 + z0);                              \
        const float n2 = e2 * (z2 + z1);                              \
        const float n3 = e3 * (z3 + z2);                              \
        z0 = n0; z1 = n1; z2 = n2; z3 = n3;                           \
        if ((cap) && (j) == 18) { r0 = z0; r1 = z1; r2 = z2; r3 = z3; rA = A; } \
        if (((j) & 3) == 3) { renormF(z0, z1, z2, z3, A);             \
                              dA = dpp_shr1_zero_i(A) - A; }          \
    }
#define DPB_STEP(eu, j)                                               \
    {                                                                 \
        HU _hu; _hu.u = (eu);                                         \
        const float e0 = (float)_hu.h.x;                              \
        const float e1 = (float)_hu.h.y;                              \
        const float e2 = (float)_hu.h.z;                              \
        const float e3 = (float)_hu.h.w;                              \
        const float w0 = z0 * e0;                                     \
        const float w1 = z1 * e1;                                     \
        const float w2 = z2 * e2;                                     \
        const float w3 = z3 * e3;                                     \
        const float q  = dpp_shl1_zero(w0);                           \
        const float pe = ldexpf(q, dA);                               \
        z0 = w0 + w1; z1 = w1 + w2; z2 = w2 + w3; z3 = w3 + pe;       \
        if (((j) & 3) == 3) { renormB(z0, z1, z2, z3, A);             \
                              dA = dpp_shl1_zero_i(A) - A; }          \
    }

    for (int s = 0; s < NSEGH; ++s) {
        const u64* cur = buf[s & 1];
        if (wv == 1) {
            if (s + 1 < NSEGH) {
                const size_t sb =
                    (size_t)(bwd ? (1980 - 20 * (s + 1)) : (1 + 20 * (s + 1))) * 400;
                stage_seg(buf[(s + 1) & 1], bbase + sb, lane);
            }
        } else if (!bwd) {
            const bool cap = (s == NSEGH - 1);   // seg 49 holds t=999 at j=18
#pragma unroll
            for (int j = 0; j < SEG; ++j) DPF_STEP(cur[j * 50 + fi], cap, j);
        } else {
#pragma unroll
            for (int j = 0; j < SEG; ++j) DPB_STEP(cur[(19 - j) * 50 + fi], j);
        }
        __syncthreads();                         // producer vmcnt(0) drain here
    }
#undef DPF_STEP
#undef DPB_STEP

    if (wv == 0) {
        if (!bwd) {
            fz[b * 64 + lane] = make_float4(r0, r1, r2, r3);
            fA[b * 64 + lane] = rA;
        } else {
            bz[b * 64 + lane] = make_float4(z0, z1, z2, z3);
            bA[b * 64 + lane] = A;
        }
    }
}

// ---------------------------------------------------------------------------
// Kernel 3: combine — scaled dot of alpha_999 and the backward row, logsumexp
// across lanes.
// ---------------------------------------------------------------------------
__global__ __launch_bounds__(64) void combine_kernel(const float4* __restrict__ fz,
                                                     const int* __restrict__ fA,
                                                     const float4* __restrict__ bz,
                                                     const int* __restrict__ bA,
                                                     float* __restrict__ part) {
    const int b = blockIdx.x;
    const int lane = threadIdx.x;
    const float4 f = fz[b * 64 + lane];
    const float4 g = bz[b * 64 + lane];
    const float s = f.x * g.x + f.y * g.y + f.z * g.z + f.w * g.w;
    float tl = (lane < 50 && s > 0.0f)
                   ? flog2(s) + (float)(fA[b * 64 + lane] + bA[b * 64 + lane])
                   : -3.0e38f;
    float m = tl;
#pragma unroll
    for (int d = 1; d < 64; d <<= 1) m = fmaxf(m, __shfl_xor(m, d, 64));
    float p = fexp2(tl - m);
#pragma unroll
    for (int d = 1; d < 64; d <<= 1) p += __shfl_xor(p, d, 64);
    if (lane == 0) part[b] = -(m + flog2(p)) * LN2;   // back to nats
}

// ---------------------------------------------------------------------------
// Kernel 4: mean over the 64 per-batch NLLs.
// ---------------------------------------------------------------------------
__global__ __launch_bounds__(64) void reduce_kernel(const float* __restrict__ part,
                                                    float* __restrict__ out) {
    float v = part[threadIdx.x];
#pragma unroll
    for (int s = 1; s < 64; s <<= 1) v += __shfl_xor(v, s, 64);
    if (threadIdx.x == 0) out[0] = v * (1.0f / BATCH);
}

// ===========================================================================
// Fallback path (round-1, natural-log domain, verified) if ws too small.
// ===========================================================================
__device__ __forceinline__ float lae(float a, float b) {
    float m = fmaxf(a, b);
    float d = fminf(a, b) - m;
    return m + __logf(1.0f + __expf(d));
}

__global__ __launch_bounds__(256) void lse_kernel(const float* __restrict__ x,
                                                  float* __restrict__ lse) {
    const int wave = threadIdx.x >> 6;
    const int lane = threadIdx.x & 63;
    const int r = blockIdx.x * 4 + wave;
    float4 v = ((const float4*)(x + (size_t)r * CVOC))[lane];
    float m = fmaxf(fmaxf(v.x, v.y), fmaxf(v.z, v.w));
#pragma unroll
    for (int s = 1; s < 64; s <<= 1) m = fmaxf(m, __shfl_xor(m, s, 64));
    float ssum = __expf(v.x - m) + __expf(v.y - m) + __expf(v.z - m) + __expf(v.w - m);
#pragma unroll
    for (int s = 1; s < 64; s <<= 1) ssum += __shfl_xor(ssum, s, 64);
    if (lane == 0) {
        const int t = r >> 6;
        const int b = r & 63;
        lse[b * T_FRAMES + t] = m + __logf(ssum);
    }
}

__global__ __launch_bounds__(64) void dp_slow_kernel(const float* __restrict__ x,
                                                     const int* __restrict__ targets,
                                                     const float* __restrict__ lse,
                                                     float* __restrict__ part) {
    __shared__ float s_lse[T_FRAMES];
    const int b = blockIdx.x;
    const int lane = threadIdx.x;
    for (int i = lane; i < T_FRAMES; i += 64) s_lse[i] = lse[b * T_FRAMES + i];
    const int* tg = targets + b * LTGT;
    const int l0 = lane * 4;
    const int i0 = tg[(l0 + 0 < LTGT) ? (l0 + 0) : (LTGT - 1)];
    const int i1 = tg[(l0 + 1 < LTGT) ? (l0 + 1) : (LTGT - 1)];
    const int i2 = tg[(l0 + 2 < LTGT) ? (l0 + 2) : (LTGT - 1)];
    const int i3 = tg[(l0 + 3 < LTGT) ? (l0 + 3) : (LTGT - 1)];
    const float* xb = x + b * CVOC;
    __syncthreads();
    float a0 = (lane == 0) ? (xb[i0] - s_lse[0]) : NEG_INF;
    float a1 = NEG_INF, a2 = NEG_INF, a3 = NEG_INF;
    const float* rA = xb + (size_t)1 * BATCH * CVOC;
    float pa0 = rA[i0], pa1 = rA[i1], pa2 = rA[i2], pa3 = rA[i3];
    const float* rB = xb + (size_t)2 * BATCH * CVOC;
    float pb0 = rB[i0], pb1 = rB[i1], pb2 = rB[i2], pb3 = rB[i3];
#define DP_STEP(e0, e1, e2, e3, tt)                                   \
    {                                                                 \
        const float ls = s_lse[tt];                                   \
        float prev = __shfl_up(a3, 1, 64);                            \
        if (lane == 0) prev = NEG_INF;                                \
        const float n0 = ((e0) - ls) + lae(a0, prev);                 \
        const float n1 = ((e1) - ls) + lae(a1, a0);                   \
        const float n2 = ((e2) - ls) + lae(a2, a1);                   \
        const float n3 = ((e3) - ls) + lae(a3, a2);                   \
        a0 = n0; a1 = n1; a2 = n2; a3 = n3;                           \
    }
    int t = 1;
    while (t < T_FRAMES) {
        DP_STEP(pa0, pa1, pa2, pa3, t);
        {
            const int tn = (t + 2 < T_FRAMES) ? (t + 2) : (T_FRAMES - 1);
            const float* r = xb + (size_t)tn * BATCH * CVOC;
            pa0 = r[i0]; pa1 = r[i1]; pa2 = r[i2]; pa3 = r[i3];
        }
        ++t;
        if (t >= T_FRAMES) break;
        DP_STEP(pb0, pb1, pb2, pb3, t);
        {
            const int tn = (t + 2 < T_FRAMES) ? (t + 2) : (T_FRAMES - 1);
            const float* r = xb + (size_t)tn * BATCH * CVOC;
            pb0 = r[i0]; pb1 = r[i1]; pb2 = r[i2]; pb3 = r[i3];
        }
        ++t;
    }
#undef DP_STEP
    const float resv = __shfl(a3, 49, 64);
    if (lane == 0) part[b] = -resv;
}

extern "C" void kernel_launch(void* const* d_in, const int* in_sizes, int n_in,
                              void* d_out, int out_size, void* d_ws, size_t ws_size,
                              hipStream_t stream) {
    const float* x = (const float*)d_in[0];        // [T, B, C] float32
    const int* targets = (const int*)d_in[1];      // [B, L] int32
    float* out = (float*)d_out;

    const size_t emit_bytes = (size_t)BATCH * T_FRAMES * EPAD * sizeof(_Float16); // 51.2 MB
    const size_t off_part = emit_bytes + 4096;
    const size_t off_fz   = emit_bytes + 8192;               // 16B aligned
    const size_t off_fA   = off_fz + (size_t)BATCH * 64 * 16;
    const size_t off_bz   = off_fA + (size_t)BATCH * 64 * 4;
    const size_t off_bA   = off_bz + (size_t)BATCH * 64 * 16;
    const size_t need     = off_bA + (size_t)BATCH * 64 * 4 + 4096;

    if (ws_size >= need) {
        _Float16* emit = (_Float16*)d_ws;
        float*  part = (float*)((char*)d_ws + off_part);
        float4* fz   = (float4*)((char*)d_ws + off_fz);
        int*    fAi  = (int*)((char*)d_ws + off_fA);
        float4* bz   = (float4*)((char*)d_ws + off_bz);
        int*    bAi  = (int*)((char*)d_ws + off_bA);
        emit_kernel<<<T_FRAMES * BATCH / 16, 256, 0, stream>>>(x, targets, emit);
        dp2_kernel<<<2 * BATCH, 128, 0, stream>>>(emit, fz, fAi, bz, bAi);
        combine_kernel<<<BATCH, 64, 0, stream>>>(fz, fAi, bz, bAi, part);
        reduce_kernel<<<1, 64, 0, stream>>>(part, out);
    } else {
        float* lse = (float*)d_ws;
        float* part = lse + (size_t)BATCH * T_FRAMES;
        lse_kernel<<<T_FRAMES * BATCH / 4, 256, 0, stream>>>(x, lse);
        dp_slow_kernel<<<BATCH, 64, 0, stream>>>(x, targets, lse, part);
        reduce_kernel<<<1, 64, 0, stream>>>(part, out);
    }
}

// Round 9
// 235.779 us; speedup vs baseline: 1.9506x; 1.0106x over previous
//
#include <hip/hip_runtime.h>

// T=2000 frames, B=64 batch, C=256 vocab, L=200 targets.
#define T_FRAMES 2000
#define BATCH    64
#define CVOC     256
#define LTGT     200
#define EPAD     200                  // emit row stride in HALVES (400 B, dense)
#define SEG      20                   // dp: rows per LDS segment (8000 B contiguous)
#define NSEGH    50                   // SEG*NSEGH = 1000 steps per direction
#define NEG_INF  (-1e30f)
#define INV_LN2  1.4426950408889634f
#define LN2      0.6931471805599453f
// emit stores PLAIN fp16 probability p = exp(x - lse). p >= ~e^-10 typical so
// no fp16 flush-to-zero; occasional subnormals lose 1-3 mantissa bits —
// irrelevant vs the 2.16e+02 absmax threshold.

#if __has_builtin(__builtin_amdgcn_exp2f)
__device__ __forceinline__ float fexp2(float x) { return __builtin_amdgcn_exp2f(x); }
#else
__device__ __forceinline__ float fexp2(float x) { return exp2f(x); }
#endif
#if __has_builtin(__builtin_amdgcn_logf)
__device__ __forceinline__ float flog2(float x) { return __builtin_amdgcn_logf(x); }
#else
__device__ __forceinline__ float flog2(float x) { return log2f(x); }
#endif

typedef unsigned long long u64;

// 4 packed fp16 emissions, 8-byte aligned (one ds_read_b64).
struct __align__(8) H4 { _Float16 x, y, z, w; };
union HU { u64 u; H4 h; };

// ---------------------------------------------------------------------------
// Staging: async global->LDS, NO VGPR in the path (r8-verified).
// global_load_lds has no destination register -> the 8 issues per segment
// cannot be serialized by regalloc; the compiler's vmcnt(0)+s_barrier drain
// at __syncthreads gives exact segment semantics (guide §5 CM#1, m97).
// Each segment = 20 contiguous rows x 400 B = 8000 B; staged as 8 x 1024 B
// (64 lanes x 16 B, LDS dest = uniform base + lane*16). 192 B over-read per
// segment stays inside the emit panel except backward seg 0 of the last
// batch, which lands in the 4 KB ws slack before 'part'.
//
// Round-9 change (consumer side): the r8 consumer read cur[j*50+fi] INSIDE
// each DP step -> scheduler left each ds_read at its use -> ~100-cyc LDS
// latency serialized into every step (measured ~120 cyc/step; issue floor is
// ~45). Hoist all 20 reads into u64 e[SEG] registers ahead of the 20-step
// chain: one basic block, independent loads visible first -> machine
// scheduler clusters them (ds_read2_b64 merges, counted lgkmcnt per m97),
// latency paid once per segment instead of per step.
// ---------------------------------------------------------------------------
__device__ __forceinline__ void stage_seg(u64* dst, const char* gseg, int lane) {
#if __has_builtin(__builtin_amdgcn_global_load_lds)
#pragma unroll
    for (int k = 0; k < 8; ++k)
        __builtin_amdgcn_global_load_lds(
            (const __attribute__((address_space(1))) void*)(gseg + k * 1024 + lane * 16),
            (__attribute__((address_space(3))) void*)((char*)dst + k * 1024),
            16, 0, 0);
#else
    // Fallback: direct copy (slower; correctness only).
#pragma unroll
    for (int k = 0; k < 8; ++k) {
        const u64* gq = (const u64*)(gseg + k * 1024);
        u64* lq = dst + k * 128;
        lq[lane * 2]     = gq[lane * 2];
        lq[lane * 2 + 1] = gq[lane * 2 + 1];
    }
#endif
}

// ---------------------------------------------------------------------------
// DPP helpers.
// ---------------------------------------------------------------------------
// wave_shr:1, 0-fill lane 0 — lane i <- lane i-1 (left neighbor).
__device__ __forceinline__ float dpp_shr1_zero(float v) {
    return __int_as_float(__builtin_amdgcn_update_dpp(
        0, __float_as_int(v), 0x138, 0xF, 0xF, true));
}
__device__ __forceinline__ int dpp_shr1_zero_i(int v) {
    return __builtin_amdgcn_update_dpp(0, v, 0x138, 0xF, 0xF, true);
}
// wave_shl:1, 0-fill lane 63 — lane i <- lane i+1 (right neighbor).
__device__ __forceinline__ float dpp_shl1_zero(float v) {
    return __int_as_float(__builtin_amdgcn_update_dpp(
        0, __float_as_int(v), 0x130, 0xF, 0xF, true));
}
__device__ __forceinline__ int dpp_shl1_zero_i(int v) {
    return __builtin_amdgcn_update_dpp(0, v, 0x130, 0xF, 0xF, true);
}
template <int CTRL, int RMASK>
__device__ __forceinline__ float dpp_term(float v) {
    return __int_as_float(__builtin_amdgcn_update_dpp(
        0, __float_as_int(v), CTRL, RMASK, 0xF, true));
}
__device__ __forceinline__ float wave_max(float v) {
    v = fmaxf(v, dpp_term<0x111, 0xF>(v));   // row_shr:1
    v = fmaxf(v, dpp_term<0x112, 0xF>(v));   // row_shr:2
    v = fmaxf(v, dpp_term<0x114, 0xF>(v));   // row_shr:4
    v = fmaxf(v, dpp_term<0x118, 0xF>(v));   // row_shr:8
    v = fmaxf(v, dpp_term<0x142, 0xA>(v));   // row_bcast:15 -> rows 1,3
    v = fmaxf(v, dpp_term<0x143, 0xC>(v));   // row_bcast:31 -> rows 2,3
    return __int_as_float(__builtin_amdgcn_readlane(__float_as_int(v), 63));
}
__device__ __forceinline__ float wave_sum(float v) {
    v += dpp_term<0x111, 0xF>(v);
    v += dpp_term<0x112, 0xF>(v);
    v += dpp_term<0x114, 0xF>(v);
    v += dpp_term<0x118, 0xF>(v);
    v += dpp_term<0x142, 0xA>(v);
    v += dpp_term<0x143, 0xC>(v);
    return __int_as_float(__builtin_amdgcn_readlane(__float_as_int(v), 63));
}

// ---------------------------------------------------------------------------
// Kernel 1: fused log-softmax + target gather -> plain fp16 probabilities.
// ---------------------------------------------------------------------------
__global__ __launch_bounds__(256) void emit_kernel(const float* __restrict__ x,
                                                   const int* __restrict__ targets,
                                                   _Float16* __restrict__ emit) {
    __shared__ float s[16][CVOC];                // 16 KB
    const int w = threadIdx.x >> 6;
    const int lane = threadIdx.x & 63;
    const int r0 = blockIdx.x * 16 + w * 4;      // this wave's 4 rows (r = t*64+b)
    const int li = (lane < 50) ? lane : 49;

    float4 v[4];
#pragma unroll
    for (int k = 0; k < 4; ++k)
        v[k] = ((const float4*)(x + (size_t)(r0 + k) * CVOC))[lane];
    int4 tg[4];
#pragma unroll
    for (int k = 0; k < 4; ++k)
        tg[k] = ((const int4*)(targets + ((r0 + k) & 63) * LTGT))[li];

    float lse2[4];
#pragma unroll
    for (int k = 0; k < 4; ++k) {
        v[k].x *= INV_LN2; v[k].y *= INV_LN2; v[k].z *= INV_LN2; v[k].w *= INV_LN2;
        float m = fmaxf(fmaxf(v[k].x, v[k].y), fmaxf(v[k].z, v[k].w));
        m = wave_max(m);
        float ss = fexp2(v[k].x - m) + fexp2(v[k].y - m) +
                   fexp2(v[k].z - m) + fexp2(v[k].w - m);
        ss = wave_sum(ss);
        lse2[k] = m + flog2(ss);
        ((float4*)&s[w * 4 + k][lane * 4])[0] = v[k];   // same-wave staging
    }

#pragma unroll
    for (int k = 0; k < 4; ++k) {
        if (lane < 50) {
            const int r = r0 + k;
            const int t = r >> 6;
            const int b = r & 63;
            H4 h;
            h.x = (_Float16)fexp2(s[w * 4 + k][tg[k].x] - lse2[k]);
            h.y = (_Float16)fexp2(s[w * 4 + k][tg[k].y] - lse2[k]);
            h.z = (_Float16)fexp2(s[w * 4 + k][tg[k].z] - lse2[k]);
            h.w = (_Float16)fexp2(s[w * 4 + k][tg[k].w] - lse2[k]);
            ((H4*)(emit + ((size_t)b * T_FRAMES + t) * EPAD))[lane] = h;
        }
    }
}

// ---------------------------------------------------------------------------
// Kernel 2: forward/backward split DP (1000 serial steps per direction),
// 2 waves/block: wave 0 computes from LDS (reads hoisted per segment),
// wave 1 stages segments via global_load_lds into the LDS double buffer.
// answer[b] = v . alpha_999 (round-3 derivation; r3/r7/r8-verified, absmax 0).
// Per-lane power-of-2 scale A; renorm every 4 steps. dA = A(neighbor)-A is
// constant between renorms -> hoisted (r5/r7/r8-verified variant).
// ---------------------------------------------------------------------------
// Forward renorm: inactive lanes adopt LEFT neighbor's scale.
__device__ __forceinline__ void renormF(float& z0, float& z1, float& z2, float& z3,
                                        int& A) {
    const float m4 = fmaxf(fmaxf(z0, z1), fmaxf(z2, z3));
    const int Ap = dpp_shr1_zero_i(A);
    const bool act = (m4 > 0.0f);
    const int sh = act ? (127 - ((__float_as_int(m4) >> 23) & 255)) : 0;
    z0 = ldexpf(z0, sh); z1 = ldexpf(z1, sh);
    z2 = ldexpf(z2, sh); z3 = ldexpf(z3, sh);
    A = act ? (A - sh) : Ap;
}
// Backward renorm: inactive lanes adopt RIGHT neighbor's scale.
__device__ __forceinline__ void renormB(float& z0, float& z1, float& z2, float& z3,
                                        int& A) {
    const float m4 = fmaxf(fmaxf(z0, z1), fmaxf(z2, z3));
    const int Ap = dpp_shl1_zero_i(A);
    const bool act = (m4 > 0.0f);
    const int sh = act ? (127 - ((__float_as_int(m4) >> 23) & 255)) : 0;
    z0 = ldexpf(z0, sh); z1 = ldexpf(z1, sh);
    z2 = ldexpf(z2, sh); z3 = ldexpf(z3, sh);
    A = act ? (A - sh) : Ap;
}

__global__ __launch_bounds__(128, 1) void dp2_kernel(const _Float16* __restrict__ emit,
                                                     float4* __restrict__ fz,
                                                     int* __restrict__ fA,
                                                     float4* __restrict__ bz,
                                                     int* __restrict__ bA) {
    __shared__ u64 buf[2][1024];                 // 2 x 8192 B (8000 used + tail)
    const int bid = blockIdx.x;
    const bool bwd = bid >= BATCH;
    const int b = bwd ? (bid - BATCH) : bid;
    const int wv = threadIdx.x >> 6;             // 0 = compute, 1 = producer
    const int lane = threadIdx.x & 63;
    const _Float16* base = emit + (size_t)b * T_FRAMES * EPAD;
    const char* bbase = (const char*)base;
    const int fi = (lane < 50) ? lane : 49;

    // Segment anchors (rows staged ASCENDING in t within each segment):
    //  forward  seg s: t = 1+20s .. 20+20s      -> step j uses LDS row j
    //  backward seg s: t = 1980-20s .. 1999-20s -> step j (t=1999-20s-j) uses row 19-j

    // compute-wave state (producer wave carries dead copies; no cost)
    float z0 = 0.0f, z1 = 0.0f, z2 = 0.0f, z3 = 0.0f;
    int A = 0, dA = 0;
    float r0 = 0.0f, r1 = 0.0f, r2 = 0.0f, r3 = 0.0f;
    int rA = 0;

    if (wv == 0) {
        if (!bwd) {
            const float e00 = (float)base[0];    // row t=0, element 0
            z0 = (lane == 0) ? e00 : 0.0f;
            renormF(z0, z1, z2, z3, A);
            dA = dpp_shr1_zero_i(A) - A;
        } else {
            z3 = (lane == 49) ? 1.0f : 0.0f;     // unit at l = 199
        }
    } else {
        const size_t sb0 = (size_t)(bwd ? 1980 : 1) * 400;
        stage_seg(buf[0], bbase + sb0, lane);    // prologue: segment 0
    }
    __syncthreads();                             // drains producer's vmcnt

#define DPF_STEP(eu, cap, j)                                          \
    {                                                                 \
        HU _hu; _hu.u = (eu);                                         \
        const float pv = dpp_shr1_zero(z3);                           \
        const float pe = ldexpf(pv, dA);                              \
        const float e0 = (float)_hu.h.x;                              \
        const float e1 = (float)_hu.h.y;                              \
        const float e2 = (float)_hu.h.z;                              \
        const float e3 = (float)_hu.h.w;                              \
        const float n0 = e0 * (z0 + pe);                              \
        const float n1 = e1 * (z1 + z0);                              \
        const float n2 = e2 * (z2 + z1);                              \
        const float n3 = e3 * (z3 + z2);                              \
        z0 = n0; z1 = n1; z2 = n2; z3 = n3;                           \
        if ((cap) && (j) == 18) { r0 = z0; r1 = z1; r2 = z2; r3 = z3; rA = A; } \
        if (((j) & 3) == 3) { renormF(z0, z1, z2, z3, A);             \
                              dA = dpp_shr1_zero_i(A) - A; }          \
    }
#define DPB_STEP(eu, j)                                               \
    {                                                                 \
        HU _hu; _hu.u = (eu);                                         \
        const float e0 = (float)_hu.h.x;                              \
        const float e1 = (float)_hu.h.y;                              \
        const float e2 = (float)_hu.h.z;                              \
        const float e3 = (float)_hu.h.w;                              \
        const float w0 = z0 * e0;                                     \
        const float w1 = z1 * e1;                                     \
        const float w2 = z2 * e2;                                     \
        const float w3 = z3 * e3;                                     \
        const float q  = dpp_shl1_zero(w0);                           \
        const float pe = ldexpf(q, dA);                               \
        z0 = w0 + w1; z1 = w1 + w2; z2 = w2 + w3; z3 = w3 + pe;       \
        if (((j) & 3) == 3) { renormB(z0, z1, z2, z3, A);             \
                              dA = dpp_shl1_zero_i(A) - A; }          \
    }

    for (int s = 0; s < NSEGH; ++s) {
        const u64* cur = buf[s & 1];
        if (wv == 1) {
            if (s + 1 < NSEGH) {
                const size_t sb =
                    (size_t)(bwd ? (1980 - 20 * (s + 1)) : (1 + 20 * (s + 1))) * 400;
                stage_seg(buf[(s + 1) & 1], bbase + sb, lane);
            }
        } else if (!bwd) {
            const bool cap = (s == NSEGH - 1);   // seg 49 holds t=999 at j=18
            u64 e[SEG];
#pragma unroll
            for (int j = 0; j < SEG; ++j) e[j] = cur[j * 50 + fi];   // hoisted reads
#pragma unroll
            for (int j = 0; j < SEG; ++j) DPF_STEP(e[j], cap, j);
        } else {
            u64 e[SEG];
#pragma unroll
            for (int j = 0; j < SEG; ++j) e[j] = cur[(19 - j) * 50 + fi];
#pragma unroll
            for (int j = 0; j < SEG; ++j) DPB_STEP(e[j], j);
        }
        __syncthreads();                         // producer vmcnt(0) drain here
    }
#undef DPF_STEP
#undef DPB_STEP

    if (wv == 0) {
        if (!bwd) {
            fz[b * 64 + lane] = make_float4(r0, r1, r2, r3);
            fA[b * 64 + lane] = rA;
        } else {
            bz[b * 64 + lane] = make_float4(z0, z1, z2, z3);
            bA[b * 64 + lane] = A;
        }
    }
}

// ---------------------------------------------------------------------------
// Kernel 3: combine — scaled dot of alpha_999 and the backward row, logsumexp
// across lanes.
// ---------------------------------------------------------------------------
__global__ __launch_bounds__(64) void combine_kernel(const float4* __restrict__ fz,
                                                     const int* __restrict__ fA,
                                                     const float4* __restrict__ bz,
                                                     const int* __restrict__ bA,
                                                     float* __restrict__ part) {
    const int b = blockIdx.x;
    const int lane = threadIdx.x;
    const float4 f = fz[b * 64 + lane];
    const float4 g = bz[b * 64 + lane];
    const float s = f.x * g.x + f.y * g.y + f.z * g.z + f.w * g.w;
    float tl = (lane < 50 && s > 0.0f)
                   ? flog2(s) + (float)(fA[b * 64 + lane] + bA[b * 64 + lane])
                   : -3.0e38f;
    float m = tl;
#pragma unroll
    for (int d = 1; d < 64; d <<= 1) m = fmaxf(m, __shfl_xor(m, d, 64));
    float p = fexp2(tl - m);
#pragma unroll
    for (int d = 1; d < 64; d <<= 1) p += __shfl_xor(p, d, 64);
    if (lane == 0) part[b] = -(m + flog2(p)) * LN2;   // back to nats
}

// ---------------------------------------------------------------------------
// Kernel 4: mean over the 64 per-batch NLLs.
// ---------------------------------------------------------------------------
__global__ __launch_bounds__(64) void reduce_kernel(const float* __restrict__ part,
                                                    float* __restrict__ out) {
    float v = part[threadIdx.x];
#pragma unroll
    for (int s = 1; s < 64; s <<= 1) v += __shfl_xor(v, s, 64);
    if (threadIdx.x == 0) out[0] = v * (1.0f / BATCH);
}

// ===========================================================================
// Fallback path (round-1, natural-log domain, verified) if ws too small.
// ===========================================================================
__device__ __forceinline__ float lae(float a, float b) {
    float m = fmaxf(a, b);
    float d = fminf(a, b) - m;
    return m + __logf(1.0f + __expf(d));
}

__global__ __launch_bounds__(256) void lse_kernel(const float* __restrict__ x,
                                                  float* __restrict__ lse) {
    const int wave = threadIdx.x >> 6;
    const int lane = threadIdx.x & 63;
    const int r = blockIdx.x * 4 + wave;
    float4 v = ((const float4*)(x + (size_t)r * CVOC))[lane];
    float m = fmaxf(fmaxf(v.x, v.y), fmaxf(v.z, v.w));
#pragma unroll
    for (int s = 1; s < 64; s <<= 1) m = fmaxf(m, __shfl_xor(m, s, 64));
    float ssum = __expf(v.x - m) + __expf(v.y - m) + __expf(v.z - m) + __expf(v.w - m);
#pragma unroll
    for (int s = 1; s < 64; s <<= 1) ssum += __shfl_xor(ssum, s, 64);
    if (lane == 0) {
        const int t = r >> 6;
        const int b = r & 63;
        lse[b * T_FRAMES + t] = m + __logf(ssum);
    }
}

__global__ __launch_bounds__(64) void dp_slow_kernel(const float* __restrict__ x,
                                                     const int* __restrict__ targets,
                                                     const float* __restrict__ lse,
                                                     float* __restrict__ part) {
    __shared__ float s_lse[T_FRAMES];
    const int b = blockIdx.x;
    const int lane = threadIdx.x;
    for (int i = lane; i < T_FRAMES; i += 64) s_lse[i] = lse[b * T_FRAMES + i];
    const int* tg = targets + b * LTGT;
    const int l0 = lane * 4;
    const int i0 = tg[(l0 + 0 < LTGT) ? (l0 + 0) : (LTGT - 1)];
    const int i1 = tg[(l0 + 1 < LTGT) ? (l0 + 1) : (LTGT - 1)];
    const int i2 = tg[(l0 + 2 < LTGT) ? (l0 + 2) : (LTGT - 1)];
    const int i3 = tg[(l0 + 3 < LTGT) ? (l0 + 3) : (LTGT - 1)];
    const float* xb = x + b * CVOC;
    __syncthreads();
    float a0 = (lane == 0) ? (xb[i0] - s_lse[0]) : NEG_INF;
    float a1 = NEG_INF, a2 = NEG_INF, a3 = NEG_INF;
    const float* rA = xb + (size_t)1 * BATCH * CVOC;
    float pa0 = rA[i0], pa1 = rA[i1], pa2 = rA[i2], pa3 = rA[i3];
    const float* rB = xb + (size_t)2 * BATCH * CVOC;
    float pb0 = rB[i0], pb1 = rB[i1], pb2 = rB[i2], pb3 = rB[i3];
#define DP_STEP(e0, e1, e2, e3, tt)                                   \
    {                                                                 \
        const float ls = s_lse[tt];                                   \
        float prev = __shfl_up(a3, 1, 64);                            \
        if (lane == 0) prev = NEG_INF;                                \
        const float n0 = ((e0) - ls) + lae(a0, prev);                 \
        const float n1 = ((e1) - ls) + lae(a1, a0);                   \
        const float n2 = ((e2) - ls) + lae(a2, a1);                   \
        const float n3 = ((e3) - ls) + lae(a3, a2);                   \
        a0 = n0; a1 = n1; a2 = n2; a3 = n3;                           \
    }
    int t = 1;
    while (t < T_FRAMES) {
        DP_STEP(pa0, pa1, pa2, pa3, t);
        {
            const int tn = (t + 2 < T_FRAMES) ? (t + 2) : (T_FRAMES - 1);
            const float* r = xb + (size_t)tn * BATCH * CVOC;
            pa0 = r[i0]; pa1 = r[i1]; pa2 = r[i2]; pa3 = r[i3];
        }
        ++t;
        if (t >= T_FRAMES) break;
        DP_STEP(pb0, pb1, pb2, pb3, t);
        {
            const int tn = (t + 2 < T_FRAMES) ? (t + 2) : (T_FRAMES - 1);
            const float* r = xb + (size_t)tn * BATCH * CVOC;
            pb0 = r[i0]; pb1 = r[i1]; pb2 = r[i2]; pb3 = r[i3];
        }
        ++t;
    }
#undef DP_STEP
    const float resv = __shfl(a3, 49, 64);
    if (lane == 0) part[b] = -resv;
}

extern "C" void kernel_launch(void* const* d_in, const int* in_sizes, int n_in,
                              void* d_out, int out_size, void* d_ws, size_t ws_size,
                              hipStream_t stream) {
    const float* x = (const float*)d_in[0];        // [T, B, C] float32
    const int* targets = (const int*)d_in[1];      // [B, L] int32
    float* out = (float*)d_out;

    const size_t emit_bytes = (size_t)BATCH * T_FRAMES * EPAD * sizeof(_Float16); // 51.2 MB
    const size_t off_part = emit_bytes + 4096;
    const size_t off_fz   = emit_bytes + 8192;               // 16B aligned
    const size_t off_fA   = off_fz + (size_t)BATCH * 64 * 16;
    const size_t off_bz   = off_fA + (size_t)BATCH * 64 * 4;
    const size_t off_bA   = off_bz + (size_t)BATCH * 64 * 16;
    const size_t need     = off_bA + (size_t)BATCH * 64 * 4 + 4096;

    if (ws_size >= need) {
        _Float16* emit = (_Float16*)d_ws;
        float*  part = (float*)((char*)d_ws + off_part);
        float4* fz   = (float4*)((char*)d_ws + off_fz);
        int*    fAi  = (int*)((char*)d_ws + off_fA);
        float4* bz   = (float4*)((char*)d_ws + off_bz);
        int*    bAi  = (int*)((char*)d_ws + off_bA);
        emit_kernel<<<T_FRAMES * BATCH / 16, 256, 0, stream>>>(x, targets, emit);
        dp2_kernel<<<2 * BATCH, 128, 0, stream>>>(emit, fz, fAi, bz, bAi);
        combine_kernel<<<BATCH, 64, 0, stream>>>(fz, fAi, bz, bAi, part);
        reduce_kernel<<<1, 64, 0, stream>>>(part, out);
    } else {
        float* lse = (float*)d_ws;
        float* part = lse + (size_t)BATCH * T_FRAMES;
        lse_kernel<<<T_FRAMES * BATCH / 4, 256, 0, stream>>>(x, lse);
        dp_slow_kernel<<<BATCH, 64, 0, stream>>>(x, targets, lse, part);
        reduce_kernel<<<1, 64, 0, stream>>>(part, out);
    }
}